// Round 1
// baseline (6816.301 us; speedup 1.0000x reference)
//
#include <hip/hip_runtime.h>
#include <hip/hip_bf16.h>

// ============================================================================
// Stacked-LSTM LM on MI355X.
// Strategy (round 1):
//   - bf16 MFMA (16x16x32) for all GEMMs, fp32 cell math + c-state.
//   - Weights packed once per call into exact B-fragment order so step kernels
//     load B frags as coalesced dwordx4. h-state kept in A-fragment order
//     (double-buffered by step parity) -> step GEMMs need no LDS, no barriers.
//   - 256 steps x 2 fused GEMM+cell kernels (grid 256, 4 waves, wave = 16-row
//     tile, block = 4 hidden units x 4 gates = 16 cols).
//   - Decoder: two 128x128-tile MFMA GEMMs with sigmoid epilogue.
// ws layout (~110 MB): WA|WB|Wd1F|Wd2F|esw|h1buf[2]|h2buf[2]|c1|c2|seq|hd
// ============================================================================

#define DI __device__ __forceinline__

typedef __attribute__((ext_vector_type(8))) short s8v;   // 8 x bf16 bits
typedef __attribute__((ext_vector_type(4))) float f4v;   // MFMA accumulator

DI f4v mfma16(s8v a, s8v b, f4v c){
  return __builtin_amdgcn_mfma_f32_16x16x32_bf16(a, b, c, 0, 0, 0);
}
DI s8v as_s8(uint4 u){ return __builtin_bit_cast(s8v, u); }

DI unsigned short f2b(float f){            // fp32 -> bf16 bits, RNE
  unsigned u = __float_as_uint(f);
  u = u + 0x7fffu + ((u >> 16) & 1u);
  return (unsigned short)(u >> 16);
}
DI float b2f(unsigned short h){ return __uint_as_float(((unsigned)h) << 16); }
DI float sig_(float x){ return 1.f / (1.f + __expf(-x)); }
DI float tanh_(float x){ return 1.f - 2.f / (__expf(2.f * x) + 1.f); } // stable both tails

// ---------------------------------------------------------------------------
// Pack [W;U] (concat along K) into B-frag order:
// dst[b(256)][ks(KS)][l(64)][e(8)] = Wcat[k][col],
//   k = 32*ks + 8*(l>>4) + e, col = 4*b + (c&3) + 1024*(c>>2), c = l&15.
// ---------------------------------------------------------------------------
__global__ __launch_bounds__(256) void k_pack_AB(const float* __restrict__ Wx,
                                                 const float* __restrict__ Ux,
                                                 unsigned short* __restrict__ dst,
                                                 int KS, int kx){
  int idx = blockIdx.x * 256 + threadIdx.x;
  if (idx >= 256 * KS * 64) return;
  int l = idx & 63, rest = idx >> 6;
  int ks = rest % KS, b = rest / KS;
  int c = l & 15;
  int col = 4 * b + (c & 3) + ((c >> 2) << 10);
  int k0 = ks * 32 + ((l >> 4) << 3);
  const float* src = (k0 < kx) ? (Wx + (size_t)k0 * 4096)
                               : (Ux + (size_t)(k0 - kx) * 4096);
  unsigned v[4];
  #pragma unroll
  for (int p = 0; p < 4; ++p){
    unsigned short lo = f2b(src[(size_t)(2 * p) * 4096 + col]);
    unsigned short hi = f2b(src[(size_t)(2 * p + 1) * 4096 + col]);
    v[p] = (unsigned)lo | ((unsigned)hi << 16);
  }
  uint4 o; o.x = v[0]; o.y = v[1]; o.z = v[2]; o.w = v[3];
  ((uint4*)dst)[idx] = o;
}

// Decoder weights: dst[cg][ks(32)][l][e] = W[k][16*cg + (l&15)], K fixed 1024.
__global__ __launch_bounds__(256) void k_pack_D(const float* __restrict__ W,
                                                unsigned short* __restrict__ dst,
                                                int CG, int N){
  int idx = blockIdx.x * 256 + threadIdx.x;
  if (idx >= CG * 32 * 64) return;
  int l = idx & 63;
  int ks = (idx >> 6) & 31;
  int cg = idx >> 11;
  int col = 16 * cg + (l & 15);
  int k0 = 32 * ks + ((l >> 4) << 3);
  unsigned v[4];
  #pragma unroll
  for (int p = 0; p < 4; ++p){
    unsigned short lo = f2b(W[(size_t)(k0 + 2 * p) * N + col]);
    unsigned short hi = f2b(W[(size_t)(k0 + 2 * p + 1) * N + col]);
    v[p] = (unsigned)lo | ((unsigned)hi << 16);
  }
  uint4 o; o.x = v[0]; o.y = v[1]; o.z = v[2]; o.w = v[3];
  ((uint4*)dst)[idx] = o;
}

// Embedding gather into A-frag order per step:
// esw[t(256)][ks(8)][w(4)][l(64)][e(8)] = emb[x[row][t]][k], row=16w+(l&15),
// k = 32*ks + 8*(l>>4) + e.
__global__ __launch_bounds__(256) void k_embed(const int* __restrict__ x,
                                               const float* __restrict__ emb,
                                               unsigned short* __restrict__ dst){
  int idx = blockIdx.x * 256 + threadIdx.x;   // < 2^19
  int l = idx & 63;
  int w = (idx >> 6) & 3;
  int ks = (idx >> 8) & 7;
  int t = idx >> 11;
  int row = 16 * w + (l & 15);
  int xi = x[row * 256 + t];
  int k0 = 32 * ks + ((l >> 4) << 3);
  const float* src = emb + (size_t)xi * 256 + k0;
  unsigned v[4];
  #pragma unroll
  for (int p = 0; p < 4; ++p){
    unsigned short lo = f2b(src[2 * p]);
    unsigned short hi = f2b(src[2 * p + 1]);
    v[p] = (unsigned)lo | ((unsigned)hi << 16);
  }
  uint4 o; o.x = v[0]; o.y = v[1]; o.z = v[2]; o.w = v[3];
  ((uint4*)dst)[idx] = o;   // idx == ((t*8+ks)*4+w)*64 + l by construction
}

// ---------------------------------------------------------------------------
// Phase A: z1 = [e_t | h1] @ [W1;U1] + b1 -> cell1 -> h1buf[(t+1)&1], c1
// grid 256 (block = 4 hidden units), 256 thr = 4 waves (wave = 16-row tile).
// ---------------------------------------------------------------------------
__global__ __launch_bounds__(256) void k_phaseA(const unsigned short* __restrict__ esw_t,
                                                const unsigned short* __restrict__ h1_in,
                                                unsigned short* __restrict__ h1_out,
                                                const unsigned short* __restrict__ WA,
                                                const float* __restrict__ b1,
                                                const int* __restrict__ x,
                                                float* __restrict__ c1, int t){
  const int blk = blockIdx.x, tid = threadIdx.x;
  const int w = tid >> 6, l = tid & 63;
  f4v acc = {0.f, 0.f, 0.f, 0.f};
  const uint4* Ap0 = (const uint4*)esw_t + w * 64 + l;   // e part, ks 0..7
  const uint4* Ap1 = (const uint4*)h1_in + w * 64 + l;   // h1 part, ks 0..31
  const uint4* Bp  = (const uint4*)WA + (size_t)blk * 40 * 64 + l;
  #pragma unroll
  for (int ks = 0; ks < 8; ++ks)
    acc = mfma16(as_s8(Ap0[ks * 256]), as_s8(Bp[ks * 64]), acc);
  #pragma unroll
  for (int ks = 0; ks < 32; ++ks)
    acc = mfma16(as_s8(Ap1[ks * 256]), as_s8(Bp[(ks + 8) * 64]), acc);

  // Epilogue: lane holds z[16w + (l>>4)*4 + q][c], c = u + 4*g.
  const int c = l & 15, u = c & 3, g = c >> 2;
  const int ug = 4 * blk + u;
  const float bias = b1[ug + (g << 10)];
  #pragma unroll
  for (int q = 0; q < 4; ++q){
    float zb = acc[q] + bias;
    float a1 = __shfl_xor(zb, 4);
    float a2 = __shfl_xor(zb, 8);
    float a3 = __shfl_xor(zb, 12);
    float v0 = zb, v1 = a1, v2 = a2, v3 = a3;   // v_j = gate (g ^ j)
    if (g & 1){ float s = v0; v0 = v1; v1 = s; s = v2; v2 = v3; v3 = s; }
    if (g & 2){ float s = v0; v0 = v2; v2 = s; s = v1; v1 = v3; v3 = s; }
    // v0=i, v1=f, v2=g, v3=o
    const int row = 16 * w + ((l >> 4) << 2) + q;
    float cold = c1[row * 1024 + ug];
    float iv = sig_(v0), fv = sig_(v1), gv = tanh_(v2), ov = sig_(v3);
    float cn = fv * cold + iv * gv;
    float hn = ov * tanh_(cn);
    const int fidx = (((ug >> 5) * 4 + (row >> 4)) * 64 + (row & 15) + (((ug >> 3) & 3) << 4)) * 8 + (ug & 7);
    bool m = (x[row * 256 + t] != 0);
    if (!m){ cn = cold; hn = b2f(h1_in[fidx]); }
    if (g == 0)      h1_out[fidx] = f2b(hn);
    else if (g == 1) c1[row * 1024 + ug] = cn;
  }
}

// ---------------------------------------------------------------------------
// Phase B: z2 = [h1n | h2] @ [W2;U2] + b2 -> cell2 -> h2buf[(t+1)&1], c2,
// out_t = m ? h2n : seq[t-1]  -> seq[:,t,:]
// ---------------------------------------------------------------------------
__global__ __launch_bounds__(256) void k_phaseB(const unsigned short* __restrict__ h1_new,
                                                const unsigned short* __restrict__ h2_in,
                                                unsigned short* __restrict__ h2_out,
                                                const unsigned short* __restrict__ WB,
                                                const float* __restrict__ b2v,
                                                const int* __restrict__ x,
                                                float* __restrict__ c2,
                                                unsigned short* __restrict__ seq, int t){
  const int blk = blockIdx.x, tid = threadIdx.x;
  const int w = tid >> 6, l = tid & 63;
  f4v acc = {0.f, 0.f, 0.f, 0.f};
  const uint4* Ap0 = (const uint4*)h1_new + w * 64 + l;  // ks 0..31 (W2 rows)
  const uint4* Ap1 = (const uint4*)h2_in  + w * 64 + l;  // ks 32..63 (U2 rows)
  const uint4* Bp  = (const uint4*)WB + (size_t)blk * 64 * 64 + l;
  #pragma unroll
  for (int ks = 0; ks < 32; ++ks)
    acc = mfma16(as_s8(Ap0[ks * 256]), as_s8(Bp[ks * 64]), acc);
  #pragma unroll
  for (int ks = 0; ks < 32; ++ks)
    acc = mfma16(as_s8(Ap1[ks * 256]), as_s8(Bp[(ks + 32) * 64]), acc);

  const int c = l & 15, u = c & 3, g = c >> 2;
  const int ug = 4 * blk + u;
  const float bias = b2v[ug + (g << 10)];
  #pragma unroll
  for (int q = 0; q < 4; ++q){
    float zb = acc[q] + bias;
    float a1 = __shfl_xor(zb, 4);
    float a2 = __shfl_xor(zb, 8);
    float a3 = __shfl_xor(zb, 12);
    float v0 = zb, v1 = a1, v2 = a2, v3 = a3;
    if (g & 1){ float s = v0; v0 = v1; v1 = s; s = v2; v2 = v3; v3 = s; }
    if (g & 2){ float s = v0; v0 = v2; v2 = s; s = v1; v1 = v3; v3 = s; }
    const int row = 16 * w + ((l >> 4) << 2) + q;
    float cold = c2[row * 1024 + ug];
    float iv = sig_(v0), fv = sig_(v1), gv = tanh_(v2), ov = sig_(v3);
    float cn = fv * cold + iv * gv;
    float hn = ov * tanh_(cn);
    const int fidx = (((ug >> 5) * 4 + (row >> 4)) * 64 + (row & 15) + (((ug >> 3) & 3) << 4)) * 8 + (ug & 7);
    bool m = (x[row * 256 + t] != 0);
    float prev = (t > 0) ? b2f(seq[(row * 256 + (t - 1)) * 1024 + ug]) : 0.f;
    float outv;
    if (m){ outv = hn; }
    else  { cn = cold; hn = b2f(h2_in[fidx]); outv = prev; }
    if (g == 0)      h2_out[fidx] = f2b(hn);
    else if (g == 1) c2[row * 1024 + ug] = cn;
    else if (g == 2) seq[(row * 256 + t) * 1024 + ug] = f2b(outv);
  }
}

// ---------------------------------------------------------------------------
// Decoder GEMM + sigmoid: out = sigmoid(A[M=16384,K=1024] @ W[K,N] + b)
// block 128x128, 4 waves x (64x64), direct global frag loads (no LDS).
// ---------------------------------------------------------------------------
__global__ __launch_bounds__(256) void k_dec(const unsigned short* __restrict__ A,
                                             const unsigned short* __restrict__ WF,
                                             const float* __restrict__ bias,
                                             void* __restrict__ outp,
                                             int N, int wf32){
  const int nb = N >> 7;
  const int rm = blockIdx.x / nb, cn = blockIdx.x - rm * nb;
  const int w = threadIdx.x >> 6, l = threadIdx.x & 63;
  const int r0 = rm * 128 + (w >> 1) * 64;
  const int c0 = cn * 128 + (w & 1) * 64;
  f4v acc[4][4];
  #pragma unroll
  for (int i = 0; i < 4; ++i)
    #pragma unroll
    for (int j = 0; j < 4; ++j) acc[i][j] = (f4v){0.f, 0.f, 0.f, 0.f};

  const uint4* WFu = (const uint4*)WF;
  #pragma unroll 4
  for (int ks = 0; ks < 32; ++ks){
    uint4 a4[4], b4[4];
    #pragma unroll
    for (int i = 0; i < 4; ++i)
      a4[i] = *(const uint4*)(A + (size_t)(r0 + 16 * i + (l & 15)) * 1024 + ks * 32 + ((l >> 4) << 3));
    #pragma unroll
    for (int j = 0; j < 4; ++j)
      b4[j] = WFu[(((c0 >> 4) + j) * 32 + ks) * 64 + l];
    #pragma unroll
    for (int i = 0; i < 4; ++i)
      #pragma unroll
      for (int j = 0; j < 4; ++j)
        acc[i][j] = mfma16(as_s8(a4[i]), as_s8(b4[j]), acc[i][j]);
  }
  #pragma unroll
  for (int j = 0; j < 4; ++j){
    const int col = c0 + 16 * j + (l & 15);
    const float bv = bias[col];
    #pragma unroll
    for (int i = 0; i < 4; ++i){
      #pragma unroll
      for (int q = 0; q < 4; ++q){
        const int row = r0 + 16 * i + ((l >> 4) << 2) + q;
        float v = sig_(acc[i][j][q] + bv);
        if (wf32) ((float*)outp)[(size_t)row * N + col] = v;
        else      ((unsigned short*)outp)[(size_t)row * N + col] = f2b(v);
      }
    }
  }
}

// ---------------------------------------------------------------------------
extern "C" void kernel_launch(void* const* d_in, const int* in_sizes, int n_in,
                              void* d_out, int out_size, void* d_ws, size_t ws_size,
                              hipStream_t stream){
  const int*   x    = (const int*)  d_in[0];
  const float* emb  = (const float*)d_in[1];
  const float* W1   = (const float*)d_in[2];
  const float* U1   = (const float*)d_in[3];
  const float* b1   = (const float*)d_in[4];
  const float* W2   = (const float*)d_in[5];
  const float* U2   = (const float*)d_in[6];
  const float* b2   = (const float*)d_in[7];
  const float* Wd1  = (const float*)d_in[8];
  const float* bd1  = (const float*)d_in[9];
  const float* Wd2  = (const float*)d_in[10];
  const float* bd2  = (const float*)d_in[11];

  char* ws = (char*)d_ws;
  // ws layout (bytes)
  unsigned short* WA   = (unsigned short*)(ws + 0);          // 10,485,760
  unsigned short* WB   = (unsigned short*)(ws + 10485760);   // 16,777,216
  unsigned short* Wd1F = (unsigned short*)(ws + 27262976);   //  2,097,152
  unsigned short* Wd2F = (unsigned short*)(ws + 29360128);   //  4,194,304
  unsigned short* esw  = (unsigned short*)(ws + 33554432);   //  8,388,608
  unsigned short* h1b  = (unsigned short*)(ws + 41943040);   //    262,144 (x2 parity)
  unsigned short* h2b  = (unsigned short*)(ws + 42205184);   //    262,144
  float*          c1   = (float*)        (ws + 42467328);    //    262,144
  float*          c2   = (float*)        (ws + 42729472);    //    262,144
  unsigned short* seq  = (unsigned short*)(ws + 42991616);   // 33,554,432
  unsigned short* hd   = (unsigned short*)(ws + 76546048);   // 33,554,432
  (void)in_sizes; (void)n_in; (void)out_size; (void)ws_size;

  // ---- setup ----
  k_pack_AB<<<2560, 256, 0, stream>>>(W1, U1, WA, 40, 256);
  k_pack_AB<<<4096, 256, 0, stream>>>(W2, U2, WB, 64, 1024);
  k_pack_D <<<512,  256, 0, stream>>>(Wd1, Wd1F, 64, 1024);
  k_pack_D <<<1024, 256, 0, stream>>>(Wd2, Wd2F, 128, 2048);
  k_embed  <<<2048, 256, 0, stream>>>(x, emb, esw);
  hipMemsetAsync(ws + 41943040, 0, 1048576, stream);  // h1b[2], h2b[2], c1, c2

  // ---- sequential scan: 256 steps x (phase A, phase B) ----
  for (int t = 0; t < 256; ++t){
    const unsigned short* esw_t = esw + (size_t)t * 16384;
    const unsigned short* h1i = h1b + (size_t)(t & 1) * 65536;
    unsigned short*       h1o = h1b + (size_t)((t + 1) & 1) * 65536;
    const unsigned short* h2i = h2b + (size_t)(t & 1) * 65536;
    unsigned short*       h2o = h2b + (size_t)((t + 1) & 1) * 65536;
    k_phaseA<<<256, 256, 0, stream>>>(esw_t, h1i, h1o, WA, b1, x, c1, t);
    k_phaseB<<<256, 256, 0, stream>>>(h1o, h2i, h2o, WB, b2, x, c2, seq, t);
  }

  // ---- decoder ----
  k_dec<<<1024, 256, 0, stream>>>(seq, Wd1F, bd1, hd,    1024, 0);
  k_dec<<<2048, 256, 0, stream>>>(hd,  Wd2F, bd2, d_out, 2048, 1);
}

// Round 2
// 6242.043 us; speedup vs baseline: 1.0920x; 1.0920x over previous
//
#include <hip/hip_runtime.h>
#include <hip/hip_bf16.h>

// ============================================================================
// Stacked-LSTM LM on MI355X — round 2: persistent-kernel scan.
//   - One kernel replaces 512 sequential launches. 128 blocks x 512 thr,
//     all co-resident (<=256 regs/wave via launch_bounds -> 2 waves/SIMD).
//   - Phase p computes L1(t=p) || L2(t=p-1)  -> 257 grid barriers total.
//   - Weights preloaded into VGPRs once (K-split 4-way per layer-wave-group),
//     partial K-sums reduced through LDS, round-1 gate/cell epilogue reused.
//   - Custom 2-level agent-scope grid barrier (8 sub-counters x 16 blocks).
// ws: WA|WB|Wd1F|Wd2F|esw|h1b[2]|h2b[2]|c1|c2|seq|hd|bar  (~105 MB)
// ============================================================================

#define DI __device__ __forceinline__

typedef __attribute__((ext_vector_type(8))) short s8v;   // 8 x bf16 bits
typedef __attribute__((ext_vector_type(4))) float f4v;   // MFMA accumulator

DI f4v mfma16(s8v a, s8v b, f4v c){
  return __builtin_amdgcn_mfma_f32_16x16x32_bf16(a, b, c, 0, 0, 0);
}
DI s8v as_s8(uint4 u){ return __builtin_bit_cast(s8v, u); }

DI unsigned short f2b(float f){            // fp32 -> bf16 bits, RNE
  unsigned u = __float_as_uint(f);
  u = u + 0x7fffu + ((u >> 16) & 1u);
  return (unsigned short)(u >> 16);
}
DI float b2f(unsigned short h){ return __uint_as_float(((unsigned)h) << 16); }
DI float sig_(float x){ return 1.f / (1.f + __expf(-x)); }
DI float tanh_(float x){ return 1.f - 2.f / (__expf(2.f * x) + 1.f); }

// ---------------------------------------------------------------------------
// Setup kernels (unchanged from round 1)
// ---------------------------------------------------------------------------
__global__ __launch_bounds__(256) void k_pack_AB(const float* __restrict__ Wx,
                                                 const float* __restrict__ Ux,
                                                 unsigned short* __restrict__ dst,
                                                 int KS, int kx){
  int idx = blockIdx.x * 256 + threadIdx.x;
  if (idx >= 256 * KS * 64) return;
  int l = idx & 63, rest = idx >> 6;
  int ks = rest % KS, b = rest / KS;
  int c = l & 15;
  int col = 4 * b + (c & 3) + ((c >> 2) << 10);
  int k0 = ks * 32 + ((l >> 4) << 3);
  const float* src = (k0 < kx) ? (Wx + (size_t)k0 * 4096)
                               : (Ux + (size_t)(k0 - kx) * 4096);
  unsigned v[4];
  #pragma unroll
  for (int p = 0; p < 4; ++p){
    unsigned short lo = f2b(src[(size_t)(2 * p) * 4096 + col]);
    unsigned short hi = f2b(src[(size_t)(2 * p + 1) * 4096 + col]);
    v[p] = (unsigned)lo | ((unsigned)hi << 16);
  }
  uint4 o; o.x = v[0]; o.y = v[1]; o.z = v[2]; o.w = v[3];
  ((uint4*)dst)[idx] = o;
}

__global__ __launch_bounds__(256) void k_pack_D(const float* __restrict__ W,
                                                unsigned short* __restrict__ dst,
                                                int CG, int N){
  int idx = blockIdx.x * 256 + threadIdx.x;
  if (idx >= CG * 32 * 64) return;
  int l = idx & 63;
  int ks = (idx >> 6) & 31;
  int cg = idx >> 11;
  int col = 16 * cg + (l & 15);
  int k0 = 32 * ks + ((l >> 4) << 3);
  unsigned v[4];
  #pragma unroll
  for (int p = 0; p < 4; ++p){
    unsigned short lo = f2b(W[(size_t)(k0 + 2 * p) * N + col]);
    unsigned short hi = f2b(W[(size_t)(k0 + 2 * p + 1) * N + col]);
    v[p] = (unsigned)lo | ((unsigned)hi << 16);
  }
  uint4 o; o.x = v[0]; o.y = v[1]; o.z = v[2]; o.w = v[3];
  ((uint4*)dst)[idx] = o;
}

__global__ __launch_bounds__(256) void k_embed(const int* __restrict__ x,
                                               const float* __restrict__ emb,
                                               unsigned short* __restrict__ dst){
  int idx = blockIdx.x * 256 + threadIdx.x;
  int l = idx & 63;
  int w = (idx >> 6) & 3;
  int ks = (idx >> 8) & 7;
  int t = idx >> 11;
  int row = 16 * w + (l & 15);
  int xi = x[row * 256 + t];
  int k0 = 32 * ks + ((l >> 4) << 3);
  const float* src = emb + (size_t)xi * 256 + k0;
  unsigned v[4];
  #pragma unroll
  for (int p = 0; p < 4; ++p){
    unsigned short lo = f2b(src[2 * p]);
    unsigned short hi = f2b(src[2 * p + 1]);
    v[p] = (unsigned)lo | ((unsigned)hi << 16);
  }
  uint4 o; o.x = v[0]; o.y = v[1]; o.z = v[2]; o.w = v[3];
  ((uint4*)dst)[idx] = o;
}

// ---------------------------------------------------------------------------
// Two-level grid barrier (128 blocks = 8 groups x 16). bar layout (ints):
//   sub[g] at bar[g*32] (g=0..7), root at bar[256], gen at bar[288].
// ---------------------------------------------------------------------------
DI void gridbar(int* bar, int target){
  __syncthreads();                      // drains each wave's stores (vmcnt 0)
  if (threadIdx.x == 0){
    __threadfence();                    // agent release: wb L2
    const int grp = blockIdx.x >> 4;
    int v = __hip_atomic_fetch_add(bar + grp * 32, 1, __ATOMIC_RELAXED,
                                   __HIP_MEMORY_SCOPE_AGENT);
    if (v == 15){
      int r = __hip_atomic_fetch_add(bar + 256, 1, __ATOMIC_RELAXED,
                                     __HIP_MEMORY_SCOPE_AGENT);
      if (r == 7){
        #pragma unroll
        for (int i = 0; i < 8; ++i)
          __hip_atomic_store(bar + i * 32, 0, __ATOMIC_RELAXED,
                             __HIP_MEMORY_SCOPE_AGENT);
        __hip_atomic_store(bar + 256, 0, __ATOMIC_RELAXED,
                           __HIP_MEMORY_SCOPE_AGENT);
        __hip_atomic_store(bar + 288, target, __ATOMIC_RELEASE,
                           __HIP_MEMORY_SCOPE_AGENT);
      }
    }
    while (__hip_atomic_load(bar + 288, __ATOMIC_RELAXED,
                             __HIP_MEMORY_SCOPE_AGENT) < target)
      __builtin_amdgcn_s_sleep(8);
    __threadfence();                    // agent acquire: inv caches
  }
  __syncthreads();
}

// ---------------------------------------------------------------------------
// Persistent scan. 128 blocks x 512 threads (8 waves).
// Waves 0-3: layer 1 (K=1280 split 4-way); waves 4-7: layer 2 (K=2048 / 4).
// Each block owns L1 cols of b' = 2*blk,2*blk+1 and same for L2 (16 cols ea).
// Phase p: L1 step t=p (p<256), L2 step t=p-1 (p>=1); 256 grid barriers.
// ---------------------------------------------------------------------------
__global__ __launch_bounds__(512, 2) void k_scan(
    const unsigned short* __restrict__ esw,
    const unsigned short* __restrict__ WA,
    const unsigned short* __restrict__ WB,
    const float* __restrict__ b1v, const float* __restrict__ b2v,
    const int* __restrict__ x,
    unsigned short* __restrict__ h1b, unsigned short* __restrict__ h2b,
    float* __restrict__ c1, float* __restrict__ c2,
    unsigned short* __restrict__ seq, int* __restrict__ bar){
  __shared__ float red[2][4][2][4][64][4];   // [lay][k4][ct][rt][l][q] 64 KB
  const int blk = blockIdx.x, tid = threadIdx.x;
  const int w = tid >> 6, l = tid & 63;
  const int lay = w >> 2, k4 = w & 3;
  const int ct_e = (w >> 1) & 1;             // epilogue col-tile
  const int rt_e0 = (w & 1) * 2;             // epilogue row-tile base
  const uint4* WAu = (const uint4*)WA;
  const uint4* WBu = (const uint4*)WB;
  const uint4* eswU = (const uint4*)esw;
  const uint4* h1U = (const uint4*)h1b;      // parity stride 8192 uint4
  const uint4* h2U = (const uint4*)h2b;

  // ---- B-weight preload into VGPRs (52 frags max = 208 regs; L1 uses 40) --
  s8v B[2][16];
  if (lay == 0){
    #pragma unroll
    for (int ct = 0; ct < 2; ++ct)
      #pragma unroll
      for (int i = 0; i < 10; ++i)
        B[ct][i] = as_s8(WAu[((size_t)(2 * blk + ct) * 40 + k4 * 10 + i) * 64 + l]);
  } else {
    #pragma unroll
    for (int ct = 0; ct < 2; ++ct)
      #pragma unroll
      for (int i = 0; i < 16; ++i)
        B[ct][i] = as_s8(WBu[((size_t)(2 * blk + ct) * 64 + k4 * 16 + i) * 64 + l]);
  }

  #pragma unroll 1
  for (int p = 0; p <= 256; ++p){
    const int par = p & 1;
    f4v acc[2][4];
    #pragma unroll
    for (int ct = 0; ct < 2; ++ct)
      #pragma unroll
      for (int rt = 0; rt < 4; ++rt) acc[ct][rt] = (f4v){0.f, 0.f, 0.f, 0.f};

    if (lay == 0){
      if (p < 256){
        const uint4* eswT = eswU + (size_t)p * 2048;
        const uint4* h1i  = h1U + par * 8192;
        #pragma unroll
        for (int c0 = 0; c0 < 10; c0 += 2){
          uint4 a[2][4];
          #pragma unroll
          for (int i = 0; i < 2; ++i){
            const int kk = k4 * 10 + c0 + i;
            const uint4* s = (kk < 8) ? (eswT + kk * 256) : (h1i + (kk - 8) * 256);
            #pragma unroll
            for (int rt = 0; rt < 4; ++rt) a[i][rt] = s[rt * 64 + l];
          }
          #pragma unroll
          for (int i = 0; i < 2; ++i)
            #pragma unroll
            for (int ct = 0; ct < 2; ++ct)
              #pragma unroll
              for (int rt = 0; rt < 4; ++rt)
                acc[ct][rt] = mfma16(as_s8(a[i][rt]), B[ct][c0 + i], acc[ct][rt]);
        }
      }
    } else {
      if (p >= 1){
        const uint4* h1n = h1U + par * 8192;         // h1 new (written phase p-1)
        const uint4* h2i = h2U + (par ^ 1) * 8192;   // h2 state in
        #pragma unroll
        for (int c0 = 0; c0 < 16; c0 += 2){
          uint4 a[2][4];
          #pragma unroll
          for (int i = 0; i < 2; ++i){
            const int kk = k4 * 16 + c0 + i;
            const uint4* s = (kk < 32) ? (h1n + kk * 256) : (h2i + (kk - 32) * 256);
            #pragma unroll
            for (int rt = 0; rt < 4; ++rt) a[i][rt] = s[rt * 64 + l];
          }
          #pragma unroll
          for (int i = 0; i < 2; ++i)
            #pragma unroll
            for (int ct = 0; ct < 2; ++ct)
              #pragma unroll
              for (int rt = 0; rt < 4; ++rt)
                acc[ct][rt] = mfma16(as_s8(a[i][rt]), B[ct][c0 + i], acc[ct][rt]);
        }
      }
    }

    // ---- K-split partials -> LDS ----
    #pragma unroll
    for (int ct = 0; ct < 2; ++ct)
      #pragma unroll
      for (int rt = 0; rt < 4; ++rt)
        *(f4v*)&red[lay][k4][ct][rt][l][0] = acc[ct][rt];
    __syncthreads();

    // ---- reduce + cell epilogue (wave handles its own layer, 2 row-tiles) --
    const bool do_epi = (lay == 0) ? (p < 256) : (p >= 1);
    if (do_epi){
      const int t = lay ? (p - 1) : p;
      const int bp = 2 * blk + ct_e;
      const int c = l & 15, u = c & 3, g = c >> 2;
      const int ug = 4 * bp + u;
      const float bv = (lay ? b2v : b1v)[ug + (g << 10)];
      float* cc = lay ? c2 : c1;
      unsigned short* hin  = lay ? (h2b + (size_t)(par ^ 1) * 65536)
                                 : (h1b + (size_t)par * 65536);
      unsigned short* hout = lay ? (h2b + (size_t)par * 65536)
                                 : (h1b + (size_t)(par ^ 1) * 65536);
      #pragma unroll
      for (int j = 0; j < 2; ++j){
        const int rt = rt_e0 + j;
        f4v z = *(f4v*)&red[lay][0][ct_e][rt][l][0];
        #pragma unroll
        for (int k = 1; k < 4; ++k)
          z += *(f4v*)&red[lay][k][ct_e][rt][l][0];
        #pragma unroll
        for (int q = 0; q < 4; ++q){
          float zb = z[q] + bv;
          float a1 = __shfl_xor(zb, 4);
          float a2 = __shfl_xor(zb, 8);
          float a3 = __shfl_xor(zb, 12);
          float v0 = zb, v1 = a1, v2 = a2, v3 = a3;   // v_j = gate (g ^ j)
          if (g & 1){ float s = v0; v0 = v1; v1 = s; s = v2; v2 = v3; v3 = s; }
          if (g & 2){ float s = v0; v0 = v2; v2 = s; s = v1; v1 = v3; v3 = s; }
          const int row = 16 * rt + ((l >> 4) << 2) + q;
          float cold = cc[row * 1024 + ug];
          float iv = sig_(v0), fv = sig_(v1), gv = tanh_(v2), ov = sig_(v3);
          float cn = fv * cold + iv * gv;
          float hn = ov * tanh_(cn);
          const int fidx = (((ug >> 5) * 4 + (row >> 4)) * 64 + (row & 15)
                            + (((ug >> 3) & 3) << 4)) * 8 + (ug & 7);
          const bool m = (x[row * 256 + t] != 0);
          if (lay == 0){
            if (!m){ cn = cold; hn = b2f(hin[fidx]); }
            if (g == 0)      hout[fidx] = f2b(hn);
            else if (g == 1) cc[row * 1024 + ug] = cn;
          } else {
            float prev = (t > 0) ? b2f(seq[((size_t)row * 256 + (t - 1)) * 1024 + ug]) : 0.f;
            float outv = hn;
            if (!m){ cn = cold; hn = b2f(hin[fidx]); outv = prev; }
            if (g == 0)      hout[fidx] = f2b(hn);
            else if (g == 1) cc[row * 1024 + ug] = cn;
            else if (g == 2) seq[((size_t)row * 256 + t) * 1024 + ug] = f2b(outv);
          }
        }
      }
    }
    if (p < 256) gridbar(bar, p + 1);
  }
}

// ---------------------------------------------------------------------------
// Decoder GEMM + sigmoid (unchanged from round 1)
// ---------------------------------------------------------------------------
__global__ __launch_bounds__(256) void k_dec(const unsigned short* __restrict__ A,
                                             const unsigned short* __restrict__ WF,
                                             const float* __restrict__ bias,
                                             void* __restrict__ outp,
                                             int N, int wf32){
  const int nb = N >> 7;
  const int rm = blockIdx.x / nb, cn = blockIdx.x - rm * nb;
  const int w = threadIdx.x >> 6, l = threadIdx.x & 63;
  const int r0 = rm * 128 + (w >> 1) * 64;
  const int c0 = cn * 128 + (w & 1) * 64;
  f4v acc[4][4];
  #pragma unroll
  for (int i = 0; i < 4; ++i)
    #pragma unroll
    for (int j = 0; j < 4; ++j) acc[i][j] = (f4v){0.f, 0.f, 0.f, 0.f};

  const uint4* WFu = (const uint4*)WF;
  #pragma unroll 4
  for (int ks = 0; ks < 32; ++ks){
    uint4 a4[4], b4[4];
    #pragma unroll
    for (int i = 0; i < 4; ++i)
      a4[i] = *(const uint4*)(A + (size_t)(r0 + 16 * i + (l & 15)) * 1024 + ks * 32 + ((l >> 4) << 3));
    #pragma unroll
    for (int j = 0; j < 4; ++j)
      b4[j] = WFu[(((c0 >> 4) + j) * 32 + ks) * 64 + l];
    #pragma unroll
    for (int i = 0; i < 4; ++i)
      #pragma unroll
      for (int j = 0; j < 4; ++j)
        acc[i][j] = mfma16(as_s8(a4[i]), as_s8(b4[j]), acc[i][j]);
  }
  #pragma unroll
  for (int j = 0; j < 4; ++j){
    const int col = c0 + 16 * j + (l & 15);
    const float bv = bias[col];
    #pragma unroll
    for (int i = 0; i < 4; ++i){
      #pragma unroll
      for (int q = 0; q < 4; ++q){
        const int row = r0 + 16 * i + ((l >> 4) << 2) + q;
        float v = sig_(acc[i][j][q] + bv);
        if (wf32) ((float*)outp)[(size_t)row * N + col] = v;
        else      ((unsigned short*)outp)[(size_t)row * N + col] = f2b(v);
      }
    }
  }
}

// ---------------------------------------------------------------------------
extern "C" void kernel_launch(void* const* d_in, const int* in_sizes, int n_in,
                              void* d_out, int out_size, void* d_ws, size_t ws_size,
                              hipStream_t stream){
  const int*   x    = (const int*)  d_in[0];
  const float* emb  = (const float*)d_in[1];
  const float* W1   = (const float*)d_in[2];
  const float* U1   = (const float*)d_in[3];
  const float* b1   = (const float*)d_in[4];
  const float* W2   = (const float*)d_in[5];
  const float* U2   = (const float*)d_in[6];
  const float* b2   = (const float*)d_in[7];
  const float* Wd1  = (const float*)d_in[8];
  const float* bd1  = (const float*)d_in[9];
  const float* Wd2  = (const float*)d_in[10];
  const float* bd2  = (const float*)d_in[11];

  char* ws = (char*)d_ws;
  unsigned short* WA   = (unsigned short*)(ws + 0);          // 10,485,760
  unsigned short* WB   = (unsigned short*)(ws + 10485760);   // 16,777,216
  unsigned short* Wd1F = (unsigned short*)(ws + 27262976);   //  2,097,152
  unsigned short* Wd2F = (unsigned short*)(ws + 29360128);   //  4,194,304
  unsigned short* esw  = (unsigned short*)(ws + 33554432);   //  8,388,608
  unsigned short* h1b  = (unsigned short*)(ws + 41943040);   //    262,144
  unsigned short* h2b  = (unsigned short*)(ws + 42205184);   //    262,144
  float*          c1   = (float*)        (ws + 42467328);    //    262,144
  float*          c2   = (float*)        (ws + 42729472);    //    262,144
  unsigned short* seq  = (unsigned short*)(ws + 42991616);   // 33,554,432
  unsigned short* hd   = (unsigned short*)(ws + 76546048);   // 33,554,432
  int*            bar  = (int*)          (ws + 110100480);   //      4,096
  (void)in_sizes; (void)n_in; (void)out_size; (void)ws_size;

  // ---- setup ----
  k_pack_AB<<<2560, 256, 0, stream>>>(W1, U1, WA, 40, 256);
  k_pack_AB<<<4096, 256, 0, stream>>>(W2, U2, WB, 64, 1024);
  k_pack_D <<<512,  256, 0, stream>>>(Wd1, Wd1F, 64, 1024);
  k_pack_D <<<1024, 256, 0, stream>>>(Wd2, Wd2F, 128, 2048);
  k_embed  <<<2048, 256, 0, stream>>>(x, emb, esw);
  hipMemsetAsync(ws + 41943040, 0, 1048576, stream);  // h1b, h2b, c1, c2
  hipMemsetAsync(ws + 110100480, 0, 4096, stream);    // barrier state

  // ---- persistent pipelined scan: 257 phases, 1 dispatch ----
  k_scan<<<128, 512, 0, stream>>>(esw, WA, WB, b1, b2, x,
                                  h1b, h2b, c1, c2, seq, bar);

  // ---- decoder ----
  k_dec<<<1024, 256, 0, stream>>>(seq, Wd1F, bd1, hd,    1024, 0);
  k_dec<<<2048, 256, 0, stream>>>(hd,  Wd2F, bd2, d_out, 2048, 1);
}